// Round 11
// baseline (1039.569 us; speedup 1.0000x reference)
//
#include <hip/hip_runtime.h>

#define TT 2
#define RR 4
#define LL 2
#define DIN 16
#define HH 256
#define CC 128
#define DOUT 4
#define EPS 1e-5f
#define NB 32   // stat buckets
#define NBG 16  // gram buckets

typedef float v4f __attribute__((ext_vector_type(4)));
typedef short bf16x8 __attribute__((ext_vector_type(8)));

__device__ __forceinline__ ushort f2bf(float x) {
    uint u = __float_as_uint(x);
    return (ushort)((u + 0x7fffu + ((u >> 16) & 1u)) >> 16);
}
__device__ __forceinline__ float bf2f(ushort h) { return __uint_as_float(((uint)h) << 16); }
__device__ __forceinline__ int swc(int c) { return c ^ ((c >> 3) & 7); }
__device__ __forceinline__ uint pack2(float x, float y) {
    return (uint)f2bf(x) | ((uint)f2bf(y) << 16);
}

// ---------------------------------------------------------------------------
// hierarchical exclusive scan
__global__ __launch_bounds__(1024) void k_scan1(const int* __restrict__ in, int* __restrict__ out,
                                                int* __restrict__ part, int n) {
    __shared__ int sm[1024];
    const int tid = threadIdx.x;
    const int i = blockIdx.x * 1024 + tid;
    const int v = (i < n) ? in[i] : 0;
    sm[tid] = v;
    __syncthreads();
    for (int off = 1; off < 1024; off <<= 1) {
        const int u = (tid >= off) ? sm[tid - off] : 0;
        __syncthreads();
        sm[tid] += u;
        __syncthreads();
    }
    if (i < n) out[i] = sm[tid] - v;
    if (tid == 1023) part[blockIdx.x] = sm[1023];
}

__global__ __launch_bounds__(1024) void k_scan2(int* __restrict__ part, int nb) {
    __shared__ int sm[1024];
    const int tid = threadIdx.x;
    const int v = (tid < nb) ? part[tid] : 0;
    sm[tid] = v;
    __syncthreads();
    for (int off = 1; off < 1024; off <<= 1) {
        const int u = (tid >= off) ? sm[tid - off] : 0;
        __syncthreads();
        sm[tid] += u;
        __syncthreads();
    }
    if (tid < nb) part[tid] = sm[tid] - v;
    if (tid == nb - 1) part[nb] = sm[tid];
}

// scan3 + optional typeStart write (pscan path) + optional dual write (cursor copy)
__global__ __launch_bounds__(1024) void k_scan3(int* __restrict__ arr, const int* __restrict__ part,
                                                int n, int nb, int* __restrict__ typeStart,
                                                int* __restrict__ out2) {
    const int i = blockIdx.x * 1024 + threadIdx.x;
    if (i < n) {
        const int v = arr[i] + part[i >> 10];
        arr[i] = v;
        if (out2) out2[i] = v;
    } else if (i == n) {
        const int total = part[nb];
        arr[n] = total;
        if (typeStart) { typeStart[0] = 0; typeStart[1] = n - total; typeStart[2] = n; }
    }
}

__global__ __launch_bounds__(256) void k_build_perm(const int* __restrict__ nt, const int* __restrict__ pscan,
                                                    const int* __restrict__ typeStart, int* __restrict__ perm,
                                                    int* __restrict__ inv, int n) {
    const int i = blockIdx.x * 256 + threadIdx.x;
    if (i >= n) return;
    const int s1 = pscan[i];
    const int pos = nt[i] ? (typeStart[1] + s1) : (i - s1);
    perm[pos] = i;
    inv[i] = pos;
}

__global__ __launch_bounds__(256) void k_deg2(const int* __restrict__ dstv, const int* __restrict__ et,
                                              const int* __restrict__ inv, int* __restrict__ rowp2, int nE) {
    const int e = blockIdx.x * 256 + threadIdx.x;
    if (e < nE) atomicAdd(&rowp2[inv[dstv[e]] * 4 + et[e]], 1);
}

__global__ __launch_bounds__(256) void k_fill2(const int* __restrict__ srcv, const int* __restrict__ dstv,
                                               const int* __restrict__ et, const int* __restrict__ inv,
                                               int* __restrict__ cur, int* __restrict__ csr, int nE) {
    const int e = blockIdx.x * 256 + threadIdx.x;
    if (e < nE) {
        const int pos = atomicAdd(&cur[inv[dstv[e]] * 4 + et[e]], 1);
        csr[pos] = inv[srcv[e]];
    }
}

// ---------------------------------------------------------------------------
// all regular weight packs in one kernel: [nmat][K][N] f32 -> [mat][K/8][N][8] bf16
__global__ __launch_bounds__(256) void k_packall(const float* __restrict__ ri_w1, const float* __restrict__ mw0,
                                                 const float* __restrict__ mw1, const float* __restrict__ ro_w0,
                                                 ushort* __restrict__ p_ri1, ushort* __restrict__ p_mw0,
                                                 ushort* __restrict__ p_mw1, ushort* __restrict__ p_ro0) {
    for (long long idx = (long long)blockIdx.x * 256 + threadIdx.x; idx < 393216;
         idx += (long long)gridDim.x * 256) {
        const float* src; ushort* dst; int K, N; long long lo;
        if (idx < 65536)       { src = ri_w1; dst = p_ri1; K = 256; N = 128; lo = idx; }
        else if (idx < 196608) { src = mw0;   dst = p_mw0; K = 128; N = 256; lo = idx - 65536; }
        else if (idx < 327680) { src = mw1;   dst = p_mw1; K = 256; N = 128; lo = idx - 196608; }
        else                   { src = ro_w0; dst = p_ro0; K = 128; N = 256; lo = idx - 327680; }
        const int kn = K * N;
        const int mat = (int)(lo / kn);
        const int rem = (int)(lo - (long long)mat * kn);
        const int k = rem / N, col = rem % N;
        dst[((size_t)mat * (K / 8) + (k >> 3)) * N * 8 + (size_t)col * 8 + (k & 7)] = f2bf(src[lo]);
    }
}

// conv stacked W: rows 0..511 = rg_w[r][kin][col], rows 512..639 = root[k][col]; blockIdx.y = layer
__global__ __launch_bounds__(256) void k_pack_conv(const float* __restrict__ rgw_all,
                                                   const float* __restrict__ root_all,
                                                   ushort* __restrict__ dst_all) {
    const int idx = blockIdx.x * 256 + threadIdx.x;
    if (idx >= 640 * 128) return;
    const int l = blockIdx.y;
    const float* rgw = rgw_all + (size_t)l * RR * CC * CC;
    const float* root = root_all + (size_t)l * CC * CC;
    ushort* dst = dst_all + (size_t)l * 640 * 128;
    const int k = idx >> 7, col = idx & 127;
    const float v = (k < 512) ? rgw[(((k >> 7) * CC) + (k & 127)) * CC + col]
                              : root[(size_t)(k - 512) * CC + col];
    dst[((size_t)(k >> 3) * CC + col) * 8 + (k & 7)] = f2bf(v);
}

// ---------------------------------------------------------------------------
// bucketed stats -> scale/shift (kept for readout only)
__global__ __launch_bounds__(512) void k_coef(const float* __restrict__ stat, const int* __restrict__ typeStart,
                                              const float* __restrict__ g, const float* __restrict__ be,
                                              float* __restrict__ scale, float* __restrict__ shift, int F) {
    const int tid = threadIdx.x;
    if (tid >= TT * F) return;
    const int t = tid / F;
    float s = 0.f, q = 0.f;
    for (int b = 0; b < NB; ++b) {
        s += stat[(size_t)b * 1024 + tid];
        q += stat[(size_t)b * 1024 + 512 + tid];
    }
    const float cnt = fmaxf((float)(typeStart[t + 1] - typeStart[t]), 1.f);
    const float mean = s / cnt;
    const float var = q / cnt - mean * mean;
    const float sc = g[tid] * rsqrtf(var + EPS);
    scale[tid] = sc;
    shift[tid] = be[tid] - mean * sc;
}

// ---------------------------------------------------------------------------
// y16 = act(bn(h))  (f32 h master -> bf16); self-computes BN coefs from stats
__global__ __launch_bounds__(256) void k_bnact(const float* __restrict__ h, const float* __restrict__ stat_in,
                                               const float* __restrict__ gg, const float* __restrict__ bb,
                                               const int* __restrict__ typeStart,
                                               ushort* __restrict__ y16, int n) {
    __shared__ float scs[2 * CC];
    __shared__ float sfs[2 * CC];
    const int tid = threadIdx.x;
    for (int idx = tid; idx < 2 * CC; idx += 256) {
        const int t = idx >> 7;
        float s = 0.f, q = 0.f;
        for (int b = 0; b < NB; ++b) {
            s += stat_in[(size_t)b * 1024 + idx];
            q += stat_in[(size_t)b * 1024 + 512 + idx];
        }
        const float cnt = fmaxf((float)(typeStart[t + 1] - typeStart[t]), 1.f);
        const float mean = s / cnt;
        const float var = q / cnt - mean * mean;
        const float sc = gg[idx] * rsqrtf(var + EPS);
        scs[idx] = sc;
        sfs[idx] = bb[idx] - mean * sc;
    }
    __syncthreads();
    const int c0 = typeStart[1];
    const long long total = (long long)n * 32;
    for (long long idx = (long long)blockIdx.x * 256 + threadIdx.x; idx < total;
         idx += (long long)gridDim.x * 256) {
        const int i = (int)(idx >> 5), cq = (int)(idx & 31);
        const int tb = (i >= c0) ? CC : 0;
        const v4f v = *(const v4f*)(h + (size_t)i * CC + cq * 4);
        float o[4];
#pragma unroll
        for (int j = 0; j < 4; ++j) {
            const float vv = fmaf(v[j], scs[tb + cq * 4 + j], sfs[tb + cq * 4 + j]);
            o[j] = fmaxf(vv, 0.01f * vv);
        }
        uint2 p = make_uint2(pack2(o[0], o[1]), pack2(o[2], o[3]));
        *(uint2*)((uint*)y16 + (size_t)i * 64 + cq * 2) = p;
    }
}

// ---------------------------------------------------------------------------
// FUSED conv: 4-relation aggregation into LDS + K=640 MFMA GEMM + h accumulate.
// Block = 64 rows, 4 waves. Phase 1: wave w aggregates rows w*16..w*16+15 into
// LDS Ab[64][512] (bf16, 16B-chunk XOR swizzle). Phase 2: GEMM vs stacked conv
// W (rows 0..511 from Ab, rows 512..639 = root operand read from y16 global).
// Epilogue: h += out + bias, h16 = bf16(h), bucketed per-type stats.
__global__ __launch_bounds__(256) void k_aggmf(
    const ushort* __restrict__ y16, const int* __restrict__ rowp2, const int* __restrict__ csr,
    const ushort* __restrict__ Wp, const float* __restrict__ Bb, const int* __restrict__ typeStart,
    float* __restrict__ Y, ushort* __restrict__ Y16, float* __restrict__ stat, int n) {
    __shared__ ushort Ab[64][512];
    __shared__ ushort Ws[2][4][128][8];

    const int tid = threadIdx.x;
    const int lane = tid & 63;
    const int wid = tid >> 6;
    const int kgrp = lane >> 4, fr = lane & 15;
    const int r0 = blockIdx.x * 64;
    if (r0 >= n) return;

    const uint* y32 = (const uint*)y16;
    uint* ab32 = (uint*)&Ab[0][0];
    const int lq = lane >> 2, lr = lane & 3;

    // ---- phase 1: gather + aggregate into swizzled LDS ----
    for (int rr = 0; rr < 16; ++rr) {
        const int m = wid * 16 + rr;
        const int i = r0 + m;
        float2 a0 = {0.f, 0.f}, a1 = {0.f, 0.f}, a2 = {0.f, 0.f}, a3 = {0.f, 0.f};
        if (i < n) {
            const int e0 = rowp2[4 * i], b1 = rowp2[4 * i + 1], b2 = rowp2[4 * i + 2],
                      b3 = rowp2[4 * i + 3], e1 = rowp2[4 * i + 4];
            for (int base = e0; base < e1; base += 64) {
                const int cnt = min(64, e1 - base);
                int pk = (lane < cnt) ? csr[base + lane] : 0;
                for (int j = 0; j < cnt; j += 8) {
                    const int mm = min(8, cnt - j);
                    uint u[8];
#pragma unroll
                    for (int k = 0; k < 8; ++k) {
                        if (k < mm) {
                            const int s = __shfl(pk, j + k);
                            u[k] = y32[(size_t)s * 64 + lane];
                        }
                    }
#pragma unroll
                    for (int k = 0; k < 8; ++k) {
                        if (k < mm) {
                            const int idx = base + j + k;
                            const float vx = bf2f((ushort)(u[k] & 0xffff));
                            const float vy = bf2f((ushort)(u[k] >> 16));
                            if (idx < b1)      { a0.x += vx; a0.y += vy; }
                            else if (idx < b2) { a1.x += vx; a1.y += vy; }
                            else if (idx < b3) { a2.x += vx; a2.y += vy; }
                            else               { a3.x += vx; a3.y += vy; }
                        }
                    }
                }
            }
        }
        const int swz = (m & 7) << 3;
        ab32[m * 256 + ((lq) ^ swz) * 4 + lr]      = pack2(a0.x, a0.y);
        ab32[m * 256 + ((16 + lq) ^ swz) * 4 + lr] = pack2(a1.x, a1.y);
        ab32[m * 256 + ((32 + lq) ^ swz) * 4 + lr] = pack2(a2.x, a2.y);
        ab32[m * 256 + ((48 + lq) ^ swz) * 4 + lr] = pack2(a3.x, a3.y);
    }

    // ---- phase 2: GEMM ----
    const int wcp = tid & 63;
    const int woffm = (wid >> 1) * 32;
    const int woffn = (wid & 1) * 64;

    auto LOADW = [&](int kt, uint4& w0, uint4& w1) {
        const ushort* wsrc = Wp + ((size_t)(kt * 4 + wid) * 128) * 8 + (size_t)wcp * 16;
        w0 = *(const uint4*)wsrc;
        w1 = *(const uint4*)(wsrc + 8);
    };
    auto STOREW = [&](int b, const uint4& w0, const uint4& w1) {
        *(uint4*)&Ws[b][wid][swc(wcp * 2)][0] = w0;
        *(uint4*)&Ws[b][wid][swc(wcp * 2 + 1)][0] = w1;
    };

    v4f acc[2][4];
#pragma unroll
    for (int mt = 0; mt < 2; ++mt)
#pragma unroll
        for (int nt = 0; nt < 4; ++nt) acc[mt][nt] = (v4f){0.f, 0.f, 0.f, 0.f};

    uint4 wA0, wA1, wB0, wB1;
    {
        uint4 t0, t1;
        LOADW(0, t0, t1);
        STOREW(0, t0, t1);
    }
    LOADW(1, wA0, wA1);
    LOADW(2, wB0, wB1);
    __syncthreads();

    const ushort* abp = (const ushort*)Ab;
    auto AFRAG = [&](int kt, int mt) -> bf16x8 {
        const int m = woffm + mt * 16 + fr;
        if (kt < 16) {
            const int chunk = (kt * 4 + kgrp) ^ ((m & 7) << 3);
            return *(const bf16x8*)(abp + (size_t)m * 512 + chunk * 8);
        } else {
            const int gr = r0 + m;
            uint4 a = make_uint4(0, 0, 0, 0);
            if (gr < n) a = *(const uint4*)(y16 + (size_t)gr * 128 + (kt - 16) * 32 + kgrp * 8);
            union { uint4 u; bf16x8 b; } cv;
            cv.u = a;
            return cv.b;
        }
    };
    auto MSTEP = [&](int b, int kt) {
        const bf16x8 aF0 = AFRAG(kt, 0);
        const bf16x8 aF1 = AFRAG(kt, 1);
        bf16x8 wf[4];
#pragma unroll
        for (int nt = 0; nt < 4; ++nt)
            wf[nt] = *(const bf16x8*)&Ws[b][kgrp][swc(woffn + nt * 16 + fr)][0];
#pragma unroll
        for (int nt = 0; nt < 4; ++nt) {
            acc[0][nt] = __builtin_amdgcn_mfma_f32_16x16x32_bf16(aF0, wf[nt], acc[0][nt], 0, 0, 0);
            acc[1][nt] = __builtin_amdgcn_mfma_f32_16x16x32_bf16(aF1, wf[nt], acc[1][nt], 0, 0, 0);
        }
    };

    for (int kt = 0; kt < 20; kt += 2) {
        MSTEP(0, kt);
        STOREW(1, wA0, wA1);
        if (kt + 3 < 20) LOADW(kt + 3, wA0, wA1);
        __syncthreads();
        MSTEP(1, kt + 1);
        if (kt + 2 < 20) {
            STOREW(0, wB0, wB1);
            if (kt + 4 < 20) LOADW(kt + 4, wB0, wB1);
            __syncthreads();
        }
    }

    // ---- epilogue: h += conv + bias; h16 = bf16(h); stats ----
    float bv[4];
#pragma unroll
    for (int nt = 0; nt < 4; ++nt) bv[nt] = Bb[woffn + nt * 16 + fr];
    const int c0 = typeStart[1];
    float cs0[4] = {0.f, 0.f, 0.f, 0.f}, cq0[4] = {0.f, 0.f, 0.f, 0.f};
    float cs1[4] = {0.f, 0.f, 0.f, 0.f}, cq1[4] = {0.f, 0.f, 0.f, 0.f};
#pragma unroll
    for (int mt = 0; mt < 2; ++mt) {
        const int grow = r0 + woffm + mt * 16 + kgrp * 4;
#pragma unroll
        for (int nt = 0; nt < 4; ++nt) {
            const int gcol = woffn + nt * 16 + fr;
#pragma unroll
            for (int rg = 0; rg < 4; ++rg) {
                const int gr = grow + rg;
                if (gr < n) {
                    float v = acc[mt][nt][rg] + bv[nt];
                    const size_t o = (size_t)gr * CC + gcol;
                    const float hv = Y[o] + v;
                    Y[o] = hv;
                    Y16[o] = f2bf(hv);
                    v = hv;
                    if (gr < c0) { cs0[nt] += v; cq0[nt] += v * v; }
                    else         { cs1[nt] += v; cq1[nt] += v * v; }
                }
            }
        }
    }
    float* sb = stat + (size_t)(blockIdx.x & (NB - 1)) * 1024;
#pragma unroll
    for (int nt = 0; nt < 4; ++nt) {
        float s = cs0[nt], q = cq0[nt];
        s += __shfl_xor(s, 16); q += __shfl_xor(q, 16);
        s += __shfl_xor(s, 32); q += __shfl_xor(q, 32);
        if (lane < 16) {
            const int col = woffn + nt * 16 + lane;
            atomicAdd(&sb[col], s);
            atomicAdd(&sb[512 + col], q);
        }
        float s1 = cs1[nt], q1 = cq1[nt];
        s1 += __shfl_xor(s1, 16); q1 += __shfl_xor(q1, 16);
        s1 += __shfl_xor(s1, 32); q1 += __shfl_xor(q1, 32);
        if (lane < 16) {
            const int col = CC + woffn + nt * 16 + lane;
            atomicAdd(&sb[col], s1);
            atomicAdd(&sb[512 + col], q1);
        }
    }
}

// ---------------------------------------------------------------------------
// Gram matrix of x per type: gram[t][bucket][272] = {G[256], s[16]}
__global__ __launch_bounds__(256) void k_gram(const float* __restrict__ x, const int* __restrict__ perm,
                                              const int* __restrict__ typeStart, float* __restrict__ gram) {
    __shared__ float Xs[256][17];
    const int tid = threadIdx.x;
    const int t = blockIdx.y;
    const int rbeg = typeStart[t], rend = typeStart[t + 1];
    const int r0 = rbeg + blockIdx.x * 1024;
    if (r0 >= rend) return;
    const int i = tid >> 4, j = tid & 15;
    float acc = 0.f, sacc = 0.f;
    for (int rr = 0; rr < 4; ++rr) {
        const int gr = r0 + rr * 256 + tid;
        v4f x0 = 0.f, x1 = 0.f, x2 = 0.f, x3 = 0.f;
        if (gr < rend) {
            const float* xr = x + (size_t)perm[gr] * DIN;
            x0 = *(const v4f*)xr; x1 = *(const v4f*)(xr + 4);
            x2 = *(const v4f*)(xr + 8); x3 = *(const v4f*)(xr + 12);
        }
        __syncthreads();
#pragma unroll
        for (int e = 0; e < 4; ++e) { Xs[tid][e] = x0[e]; Xs[tid][4 + e] = x1[e];
                                      Xs[tid][8 + e] = x2[e]; Xs[tid][12 + e] = x3[e]; }
        __syncthreads();
        for (int r = 0; r < 256; ++r) acc += Xs[r][i] * Xs[r][j];
        if (tid < 16)
            for (int r = 0; r < 256; ++r) sacc += Xs[r][tid];
        __syncthreads();
    }
    float* gb = gram + ((size_t)t * NBG + (blockIdx.x & (NBG - 1))) * 272;
    atomicAdd(&gb[tid], acc);
    if (tid < 16) atomicAdd(&gb[256 + tid], sacc);
}

// analytic readin BN coef, folded into effective W0', b0'
__global__ __launch_bounds__(512) void k_ri_coef(const float* __restrict__ gram, const int* __restrict__ typeStart,
                                                 const float* __restrict__ ri_w0, const float* __restrict__ ri_b0,
                                                 const float* __restrict__ g, const float* __restrict__ be,
                                                 float* __restrict__ w0eff, float* __restrict__ b0eff) {
    __shared__ float G[2][272];
    const int tid = threadIdx.x;
    for (int idx = tid; idx < 2 * 272; idx += 512) {
        const int tt = idx / 272, k = idx % 272;
        float s = 0.f;
        for (int b = 0; b < NBG; ++b) s += gram[((size_t)tt * NBG + b) * 272 + k];
        G[tt][k] = s;
    }
    __syncthreads();
    const int t = tid >> 8, c = tid & 255;
    float wv[16];
#pragma unroll
    for (int k = 0; k < 16; ++k) wv[k] = ri_w0[((size_t)t * 16 + k) * HH + c];
    const float b = ri_b0[t * HH + c];
    const float cnt = fmaxf((float)(typeStart[t + 1] - typeStart[t]), 1.f);
    float sw = 0.f;
#pragma unroll
    for (int k = 0; k < 16; ++k) sw += G[t][256 + k] * wv[k];
    const float mean = (sw + cnt * b) / cnt;
    float e2 = 0.f;
#pragma unroll
    for (int i = 0; i < 16; ++i) {
        const float wi = wv[i];
#pragma unroll
        for (int j = 0; j < 16; ++j) e2 += wi * wv[j] * G[t][i * 16 + j];
    }
    e2 = (e2 + 2.f * b * sw + cnt * b * b) / cnt;
    const float var = e2 - mean * mean;
    const float sc = g[t * HH + c] * rsqrtf(var + EPS);
    const float sf = be[t * HH + c] - mean * sc;
    b0eff[t * HH + c] = b * sc + sf;
#pragma unroll
    for (int k = 0; k < 16; ++k) w0eff[((size_t)t * 16 + k) * HH + c] = wv[k] * sc;
}

// ---------------------------------------------------------------------------
// fused readin: h = act(x@W0'+b0') @ ri_w1 + ri_b1 ; writes h, h16, stats slot
__global__ __launch_bounds__(256) void k_readin(const float* __restrict__ x, const int* __restrict__ perm,
                                                const int* __restrict__ typeStart,
                                                const float* __restrict__ w0eff, const float* __restrict__ b0eff,
                                                const ushort* __restrict__ Wp, const float* __restrict__ b1,
                                                float* __restrict__ h, ushort* __restrict__ h16,
                                                float* __restrict__ stat) {
    __shared__ float Xs[128][17];
    __shared__ float W0s[16][256];
    __shared__ float b0s[256];
    __shared__ ushort As[128][40];
    __shared__ ushort Ws[4][128][8];

    const int tid = threadIdx.x;
    const int lane = tid & 63;
    const int wid = tid >> 6;
    const int woffm = (wid >> 1) * 64, woffn = (wid & 1) * 64;
    const int t = blockIdx.y;
    const int rbeg = typeStart[t], rend = typeStart[t + 1];
    const int r0 = rbeg + blockIdx.x * 128;
    if (r0 >= rend) return;

    for (int idx = tid; idx < 16 * 256; idx += 256) W0s[idx >> 8][idx & 255] = w0eff[(size_t)t * 4096 + idx];
    if (tid < 256) b0s[tid] = b0eff[t * 256 + tid];

    const int srow = tid >> 1, half = tid & 1;
    const int sgr = r0 + srow;
    const bool svalid = sgr < rend;
    {
        v4f x0 = 0.f, x1 = 0.f;
        if (svalid) {
            const float* xr = x + (size_t)perm[sgr] * DIN + half * 8;
            x0 = *(const v4f*)xr; x1 = *(const v4f*)(xr + 4);
        }
#pragma unroll
        for (int e = 0; e < 4; ++e) { Xs[srow][half * 8 + e] = x0[e]; Xs[srow][half * 8 + 4 + e] = x1[e]; }
    }
    __syncthreads();
    float xr[16];
#pragma unroll
    for (int k = 0; k < 16; ++k) xr[k] = Xs[srow][k];

    v4f acc[4][4];
#pragma unroll
    for (int mt = 0; mt < 4; ++mt)
#pragma unroll
        for (int nt = 0; nt < 4; ++nt) acc[mt][nt] = (v4f){0.f, 0.f, 0.f, 0.f};

    const size_t wmat = (size_t)t * 256 * 128;
    const int wcp = tid & 63;

    for (int kt = 0; kt < 8; ++kt) {
        const int k0 = kt * 32;
        ushort hA[16];
#pragma unroll
        for (int c2 = 0; c2 < 16; ++c2) {
            const int col = k0 + half * 16 + c2;
            float d = b0s[col];
#pragma unroll
            for (int k = 0; k < 16; ++k) d = fmaf(xr[k], W0s[k][col], d);
            d = fmaxf(d, 0.01f * d);
            hA[c2] = f2bf(d);
        }
        const ushort* wsrc = Wp + wmat + ((size_t)(k0 / 8 + wid) * 128) * 8 + (size_t)wcp * 16;
        const uint4 w0 = *(const uint4*)wsrc;
        const uint4 w1 = *(const uint4*)(wsrc + 8);
        __syncthreads();
        *(uint4*)&As[srow][half * 16] = *(uint4*)&hA[0];
        *(uint4*)&As[srow][half * 16 + 8] = *(uint4*)&hA[8];
        *(uint4*)&Ws[wid][swc(wcp * 2)][0] = w0;
        *(uint4*)&Ws[wid][swc(wcp * 2 + 1)][0] = w1;
        __syncthreads();
        const int afr = lane & 15;
        const int akg = (lane >> 4) * 8;
        bf16x8 aF[4], wf[4];
#pragma unroll
        for (int mt = 0; mt < 4; ++mt) aF[mt] = *(const bf16x8*)&As[woffm + mt * 16 + afr][akg];
#pragma unroll
        for (int nt = 0; nt < 4; ++nt) wf[nt] = *(const bf16x8*)&Ws[lane >> 4][swc(woffn + nt * 16 + afr)][0];
#pragma unroll
        for (int mt = 0; mt < 4; ++mt)
#pragma unroll
            for (int nt = 0; nt < 4; ++nt)
                acc[mt][nt] = __builtin_amdgcn_mfma_f32_16x16x32_bf16(aF[mt], wf[nt], acc[mt][nt], 0, 0, 0);
    }

    float bv[4];
#pragma unroll
    for (int nt = 0; nt < 4; ++nt) bv[nt] = b1[t * 128 + woffn + nt * 16 + (lane & 15)];
    float cs[4] = {0.f, 0.f, 0.f, 0.f}, cq[4] = {0.f, 0.f, 0.f, 0.f};
#pragma unroll
    for (int mt = 0; mt < 4; ++mt) {
        const int grow = r0 + woffm + mt * 16 + (lane >> 4) * 4;
#pragma unroll
        for (int nt = 0; nt < 4; ++nt) {
            const int gcol = woffn + nt * 16 + (lane & 15);
#pragma unroll
            for (int rg = 0; rg < 4; ++rg) {
                const int gr = grow + rg;
                if (gr < rend) {
                    const float v = acc[mt][nt][rg] + bv[nt];
                    const size_t o = (size_t)gr * 128 + gcol;
                    h[o] = v;
                    h16[o] = f2bf(v);
                    cs[nt] += v; cq[nt] += v * v;
                }
            }
        }
    }
    float* sb = stat + (size_t)(blockIdx.x & (NB - 1)) * 1024;
#pragma unroll
    for (int nt = 0; nt < 4; ++nt) {
        float s = cs[nt], q = cq[nt];
        s += __shfl_xor(s, 16); q += __shfl_xor(q, 16);
        s += __shfl_xor(s, 32); q += __shfl_xor(q, 32);
        if (lane < 16) {
            const int col = t * 128 + woffn + nt * 16 + lane;
            atomicAdd(&sb[col], s);
            atomicAdd(&sb[512 + col], q);
        }
    }
}

// ---------------------------------------------------------------------------
// LDS-staged MFMA GEMM, BM=64 tile, double-buffered LDS, depth-2 prefetch,
// ONE barrier per k-step. X bf16 row-linear.
// BNIN: self-computed BN coefs (stat_in,g,be) + leaky on input.
// OUTMODE 0: Y=f32; 1: Y16=bf16; 2: h-accumulate (Y+=, Y16=bf16(h)).
template <int K, int OUTW, bool TYPED, bool WHET, bool BNIN, bool BHET, bool STATS, int OUTMODE>
__global__ __launch_bounds__(256) void k_mf(
    const ushort* __restrict__ Xb, const ushort* __restrict__ Wp, const float* __restrict__ Bb,
    const float* __restrict__ stat_in, const float* __restrict__ gg,
    const float* __restrict__ bb, const int* __restrict__ typeStart,
    float* __restrict__ Y, ushort* __restrict__ Y16, float* __restrict__ stat,
    int rbeg_u, int rend_u) {
    constexpr int NT = K / 32;

    __shared__ ushort As[2][64][40];
    __shared__ ushort Ws[2][4][128][8];
    __shared__ float csh[BNIN ? K : 1];
    __shared__ float cfh[BNIN ? K : 1];

    const int tid = threadIdx.x;
    const int lane = tid & 63;
    const int wid = tid >> 6;
    const int kgrp = lane >> 4, fr = lane & 15;
    const int woffm = (wid >> 1) * 32;
    const int woffn = (wid & 1) * 64;

    int t = 0, rbeg = rbeg_u, rend = rend_u;
    if constexpr (TYPED) { t = blockIdx.y; rbeg = typeStart[t]; rend = typeStart[t + 1]; }
    const int r0 = rbeg + blockIdx.x * 64;
    if (r0 >= rend) return;
    const int zoff = (OUTW == 256) ? blockIdx.z * 128 : 0;

    if constexpr (BNIN) {
        const float cnt = fmaxf((float)(typeStart[t + 1] - typeStart[t]), 1.f);
        for (int k = tid; k < K; k += 256) {
            float s = 0.f, q = 0.f;
            for (int b = 0; b < NB; ++b) {
                s += stat_in[(size_t)b * 1024 + t * K + k];
                q += stat_in[(size_t)b * 1024 + 512 + t * K + k];
            }
            const float mean = s / cnt;
            const float var = q / cnt - mean * mean;
            const float sc = gg[t * K + k] * rsqrtf(var + EPS);
            csh[k] = sc;
            cfh[k] = bb[t * K + k] - mean * sc;
        }
        __syncthreads();
    }

    const int srow = tid >> 2, skq = tid & 3;
    const int sgr = r0 + srow;
    const bool sv = sgr < rend;
    const int wcp = tid & 63;
    const size_t wmat = (size_t)(WHET ? t : 0) * K * OUTW;

    auto LOADA = [&](int kt) -> uint4 {
        const int k0 = kt * 32;
        uint4 a = make_uint4(0, 0, 0, 0);
        if (sv) a = *(const uint4*)(Xb + (size_t)sgr * K + k0 + skq * 8);
        if constexpr (BNIN) {
            uint ua[4] = {a.x, a.y, a.z, a.w};
#pragma unroll
            for (int e = 0; e < 4; ++e) {
                const int k = kt * 32 + skq * 8 + 2 * e;
                float f0 = fmaf(bf2f((ushort)(ua[e] & 0xffff)), csh[k], cfh[k]);
                float f1 = fmaf(bf2f((ushort)(ua[e] >> 16)), csh[k + 1], cfh[k + 1]);
                f0 = fmaxf(f0, 0.01f * f0);
                f1 = fmaxf(f1, 0.01f * f1);
                ua[e] = pack2(f0, f1);
            }
            a = make_uint4(ua[0], ua[1], ua[2], ua[3]);
        }
        return a;
    };
    auto LOADW = [&](int kt, uint4& w0, uint4& w1) {
        const ushort* wsrc = Wp + wmat + ((size_t)(kt * 4 + wid) * OUTW + zoff) * 8 + (size_t)wcp * 16;
        w0 = *(const uint4*)wsrc;
        w1 = *(const uint4*)(wsrc + 8);
    };
    auto STORE = [&](int b, const uint4& a, const uint4& w0, const uint4& w1) {
        *(uint4*)&As[b][srow][skq * 8] = a;
        *(uint4*)&Ws[b][wid][swc(wcp * 2)][0] = w0;
        *(uint4*)&Ws[b][wid][swc(wcp * 2 + 1)][0] = w1;
    };

    v4f acc[2][4];
#pragma unroll
    for (int mt = 0; mt < 2; ++mt)
#pragma unroll
        for (int nt = 0; nt < 4; ++nt) acc[mt][nt] = (v4f){0.f, 0.f, 0.f, 0.f};

    auto MSTEP = [&](int b) {
        const bf16x8 aF0 = *(const bf16x8*)&As[b][woffm + fr][kgrp * 8];
        const bf16x8 aF1 = *(const bf16x8*)&As[b][woffm + 16 + fr][kgrp * 8];
        bf16x8 wf[4];
#pragma unroll
        for (int nt = 0; nt < 4; ++nt)
            wf[nt] = *(const bf16x8*)&Ws[b][kgrp][swc(woffn + nt * 16 + fr)][0];
#pragma unroll
        for (int nt = 0; nt < 4; ++nt) {
            acc[0][nt] = __builtin_amdgcn_mfma_f32_16x16x32_bf16(aF0, wf[nt], acc[0][nt], 0, 0, 0);
            acc[1][nt] = __builtin_amdgcn_mfma_f32_16x16x32_bf16(aF1, wf[nt], acc[1][nt], 0, 0, 0);
        }
    };

    uint4 aA = make_uint4(0, 0, 0, 0), wA0 = aA, wA1 = aA;
    uint4 aB = aA, wB0 = aA, wB1 = aA;
    {
        uint4 a0 = LOADA(0), w0, w1;
        LOADW(0, w0, w1);
        STORE(0, a0, w0, w1);
    }
    if (NT > 1) { aA = LOADA(1); LOADW(1, wA0, wA1); }
    if (NT > 2) { aB = LOADA(2); LOADW(2, wB0, wB1); }
    __syncthreads();

#pragma unroll
    for (int kt = 0; kt < NT; kt += 2) {
        MSTEP(0);
        {
            STORE(1, aA, wA0, wA1);
            if (kt + 3 < NT) { aA = LOADA(kt + 3); LOADW(kt + 3, wA0, wA1); }
            __syncthreads();
        }
        MSTEP(1);
        if (kt + 2 < NT) {
            STORE(0, aB, wB0, wB1);
            if (kt + 4 < NT) { aB = LOADA(kt + 4); LOADW(kt + 4, wB0, wB1); }
            __syncthreads();
        }
    }

    // ---- epilogue ----
    const float* BbT = Bb + (BHET ? (size_t)t * OUTW : 0);
    float bv[4];
#pragma unroll
    for (int nt = 0; nt < 4; ++nt) bv[nt] = BbT[zoff + woffn + nt * 16 + fr];
    const int c0 = (STATS && !TYPED) ? typeStart[1] : 0;
    float cs0[4] = {0.f, 0.f, 0.f, 0.f}, cq0[4] = {0.f, 0.f, 0.f, 0.f};
    float cs1[4] = {0.f, 0.f, 0.f, 0.f}, cq1[4] = {0.f, 0.f, 0.f, 0.f};
#pragma unroll
    for (int mt = 0; mt < 2; ++mt) {
        const int grow = r0 + woffm + mt * 16 + kgrp * 4;
#pragma unroll
        for (int nt = 0; nt < 4; ++nt) {
            const int gcol = zoff + woffn + nt * 16 + fr;
#pragma unroll
            for (int rg = 0; rg < 4; ++rg) {
                const int gr = grow + rg;
                if (gr < rend) {
                    float v = acc[mt][nt][rg] + bv[nt];
                    const size_t o = (size_t)gr * OUTW + gcol;
                    if constexpr (OUTMODE == 0) Y[o] = v;
                    if constexpr (OUTMODE == 1) Y16[o] = f2bf(v);
                    if constexpr (OUTMODE == 2) {
                        const float hv = Y[o] + v;
                        Y[o] = hv;
                        Y16[o] = f2bf(hv);
                        v = hv;
                    }
                    if constexpr (STATS) {
                        if (TYPED || gr < c0) { cs0[nt] += v; cq0[nt] += v * v; }
                        else                  { cs1[nt] += v; cq1[nt] += v * v; }
                    }
                }
            }
        }
    }
    if constexpr (STATS) {
        float* sb = stat + (size_t)(blockIdx.x & (NB - 1)) * 1024;
#pragma unroll
        for (int nt = 0; nt < 4; ++nt) {
            float s = cs0[nt], q = cq0[nt];
            s += __shfl_xor(s, 16); q += __shfl_xor(q, 16);
            s += __shfl_xor(s, 32); q += __shfl_xor(q, 32);
            if (lane < 16) {
                const int col = t * OUTW + zoff + woffn + nt * 16 + lane;
                atomicAdd(&sb[col], s);
                atomicAdd(&sb[512 + col], q);
            }
            if constexpr (!TYPED) {
                float s1 = cs1[nt], q1 = cq1[nt];
                s1 += __shfl_xor(s1, 16); q1 += __shfl_xor(q1, 16);
                s1 += __shfl_xor(s1, 32); q1 += __shfl_xor(q1, 32);
                if (lane < 16) {
                    const int col = OUTW + zoff + woffn + nt * 16 + lane;
                    atomicAdd(&sb[col], s1);
                    atomicAdd(&sb[512 + col], q1);
                }
            }
        }
    }
}

// ---------------------------------------------------------------------------
// readout stage 2: out[perm[i]] = act(bn(A256b[i])) @ ro_w1[t] + ro_b1[t]
__global__ __launch_bounds__(256) void k_ro1(const ushort* __restrict__ A256b, const int* __restrict__ perm,
                                             const int* __restrict__ typeStart, const float* __restrict__ ro_w1,
                                             const float* __restrict__ ro_b1, const float* __restrict__ scale,
                                             const float* __restrict__ shift, float* __restrict__ out, int n) {
    __shared__ float W1s[2][256][4];
    __shared__ float scs[512];
    __shared__ float sfs[512];
    const int tid = threadIdx.x;
    for (int idx = tid; idx < 2048; idx += 256) {
        const int t = idx >> 10, rem = idx & 1023;
        W1s[t][rem >> 2][rem & 3] = ro_w1[idx];
    }
    for (int idx = tid; idx < 512; idx += 256) { scs[idx] = scale[idx]; sfs[idx] = shift[idx]; }
    __syncthreads();
    const int trow = tid >> 2, sub = tid & 3;
    const int gr = blockIdx.x * 64 + trow;
    if (gr >= n) return;
    const int c0 = typeStart[1];
    const int t = (gr >= c0) ? 1 : 0;
    v4f acc = 0.f;
    const ushort* ar = A256b + (size_t)gr * 256 + sub * 64;
#pragma unroll
    for (int q = 0; q < 8; ++q) {
        const uint4 u = *(const uint4*)(ar + q * 8);
        const uint uw[4] = {u.x, u.y, u.z, u.w};
#pragma unroll
        for (int e = 0; e < 4; ++e) {
#pragma unroll
            for (int hl = 0; hl < 2; ++hl) {
                const int col = sub * 64 + q * 8 + 2 * e + hl;
                const float v = bf2f((ushort)(hl ? (uw[e] >> 16) : (uw[e] & 0xffff)));
                float vv = fmaf(v, scs[t * 256 + col], sfs[t * 256 + col]);
                vv = fmaxf(vv, 0.01f * vv);
                acc += vv * *(const v4f*)&W1s[t][col][0];
            }
        }
    }
#pragma unroll
    for (int e = 0; e < 4; ++e) { acc[e] += __shfl_xor(acc[e], 1); acc[e] += __shfl_xor(acc[e], 2); }
    if (sub == 0) {
        acc += *(const v4f*)(ro_b1 + t * 4);
        *(v4f*)(out + (size_t)perm[gr] * 4) = acc;
    }
}

// ---------------------------------------------------------------------------
extern "C" void kernel_launch(void* const* d_in, const int* in_sizes, int n_in,
                              void* d_out, int out_size, void* d_ws, size_t ws_size,
                              hipStream_t stream) {
    const float* x = (const float*)d_in[0];
    const int* ei = (const int*)d_in[1];
    const int* nt = (const int*)d_in[2];
    const int* et = (const int*)d_in[3];
    const float* ri_w0 = (const float*)d_in[4];
    const float* ri_b0 = (const float*)d_in[5];
    const float* ri_g0 = (const float*)d_in[6];
    const float* ri_be0 = (const float*)d_in[7];
    const float* ri_w1 = (const float*)d_in[8];
    const float* ri_b1 = (const float*)d_in[9];
    const float* cn_g = (const float*)d_in[10];
    const float* cn_b = (const float*)d_in[11];
    const float* rg_w = (const float*)d_in[12];
    const float* rg_root = (const float*)d_in[13];
    const float* rg_bias = (const float*)d_in[14];
    const float* mn_g = (const float*)d_in[15];
    const float* mn_b = (const float*)d_in[16];
    const float* mw0 = (const float*)d_in[17];
    const float* mb0 = (const float*)d_in[18];
    const float* mg0 = (const float*)d_in[19];
    const float* mbe0 = (const float*)d_in[20];
    const float* mw1 = (const float*)d_in[21];
    const float* mb1 = (const float*)d_in[22];
    const float* ro_w0 = (const float*)d_in[23];
    const float* ro_b0 = (const float*)d_in[24];
    const float* ro_g0 = (const float*)d_in[25];
    const float* ro_be0 = (const float*)d_in[26];
    const float* ro_w1 = (const float*)d_in[27];
    const float* ro_b1 = (const float*)d_in[28];

    const int n = in_sizes[2];
    const int nE = in_sizes[3];
    const int* srcv = ei;
    const int* dstv = ei + nE;

    // ---- workspace ----
    char* w = (char*)d_ws;
    size_t off = 0;
    auto alloc = [&](size_t bytes) -> char* {
        char* p = w + off;
        off = (off + bytes + 255) & ~(size_t)255;
        return p;
    };
    float* h = (float*)alloc((size_t)n * CC * sizeof(float));
    ushort* h16 = (ushort*)alloc((size_t)(n + 128) * CC * sizeof(ushort));
    int* csr = (int*)alloc((size_t)nE * sizeof(int));
    int* rowp2 = (int*)alloc(((size_t)4 * n + 1) * sizeof(int));
    int* cur2 = (int*)alloc((size_t)4 * n * sizeof(int));
    int* perm = (int*)alloc((size_t)n * sizeof(int));
    int* inv = (int*)alloc((size_t)n * sizeof(int));
    int* pscan = (int*)alloc((size_t)(n + 1) * sizeof(int));
    int* part = (int*)alloc(2052 * sizeof(int));
    int* typeStart = (int*)alloc(64);
    float* statgram = (float*)alloc(((size_t)9 * NB * 1024 + 2 * NBG * 272) * sizeof(float));
    float* scale = (float*)alloc(512 * sizeof(float));
    float* shift = (float*)alloc(512 * sizeof(float));
    float* w0eff = (float*)alloc((size_t)2 * 16 * 256 * sizeof(float));
    float* b0eff = (float*)alloc(512 * sizeof(float));
    ushort* pw_ri1 = (ushort*)alloc(65536 * 2);
    ushort* pw_mw0 = (ushort*)alloc(131072 * 2);
    ushort* pw_mw1 = (ushort*)alloc(131072 * 2);
    ushort* pw_ro0 = (ushort*)alloc(65536 * 2);
    ushort* pw_conv = (ushort*)alloc(163840 * 2);
    char* region2 = alloc((size_t)(n + 128) * 512);  // A256b bf16 | y16 (disjoint lifetimes)
    if (ws_size < off) return;

    float* statbuf = statgram;
    float* gram = statgram + (size_t)9 * NB * 1024;
    ushort* A256b = (ushort*)region2;
    ushort* y16 = (ushort*)region2;  // first n*256 bytes of region2
    float* out = (float*)d_out;

    auto SS = [&](int slot) { return statbuf + (size_t)slot * NB * 1024; };

    const int gE = (nE + 255) / 256;
    const int gN = (n + 255) / 256;
    const int nb = (n + 1023) / 1024;
    const int m4 = 4 * n;
    const int nb2 = (m4 + 1023) / 1024;
    const int gmx = (n + 127) / 128;
    const int gm64 = (n + 63) / 64;

    // ---- weight packing ----
    k_packall<<<1536, 256, 0, stream>>>(ri_w1, mw0, mw1, ro_w0, pw_ri1, pw_mw0, pw_mw1, pw_ro0);
    k_pack_conv<<<dim3(320, 2), 256, 0, stream>>>(rg_w, rg_root, pw_conv);

    // ---- setup ----
    hipMemsetAsync(statgram, 0, ((size_t)9 * NB * 1024 + 2 * NBG * 272) * sizeof(float), stream);
    k_scan1<<<nb, 1024, 0, stream>>>(nt, pscan, part, n);
    k_scan2<<<1, 1024, 0, stream>>>(part, nb);
    k_scan3<<<(n + 1024) / 1024, 1024, 0, stream>>>(pscan, part, n, nb, typeStart, nullptr);
    k_build_perm<<<gN, 256, 0, stream>>>(nt, pscan, typeStart, perm, inv, n);
    hipMemsetAsync(rowp2, 0, ((size_t)m4 + 1) * sizeof(int), stream);
    k_deg2<<<gE, 256, 0, stream>>>(dstv, et, inv, rowp2, nE);
    k_scan1<<<nb2, 1024, 0, stream>>>(rowp2, rowp2, part, m4);
    k_scan2<<<1, 1024, 0, stream>>>(part, nb2);
    k_scan3<<<(m4 + 1024) / 1024, 1024, 0, stream>>>(rowp2, part, m4, nb2, nullptr, cur2);
    k_fill2<<<gE, 256, 0, stream>>>(srcv, dstv, et, inv, cur2, csr, nE);

    // ---- readin (fused): gram -> analytic coef -> x->h ----
    k_gram<<<dim3((n + 1023) / 1024, 2), 256, 0, stream>>>(x, perm, typeStart, gram);
    k_ri_coef<<<1, 512, 0, stream>>>(gram, typeStart, ri_w0, ri_b0, ri_g0, ri_be0, w0eff, b0eff);
    k_readin<<<dim3(gmx, 2), 256, 0, stream>>>(x, perm, typeStart, w0eff, b0eff, pw_ri1, ri_b1,
                                               h, h16, SS(1));

    // ---- RES+ layers ----
    for (int l = 0; l < LL; ++l) {
        const int s_cn = l ? 4 : 1, s_mn = l ? 5 : 2, s_mg = l ? 6 : 3, s_nx = l ? 7 : 4;
        k_bnact<<<1280, 256, 0, stream>>>(h, SS(s_cn), cn_g + (size_t)l * TT * CC,
                                          cn_b + (size_t)l * TT * CC, typeStart, y16, n);
        k_aggmf<<<gm64, 256, 0, stream>>>(y16, rowp2, csr, pw_conv + (size_t)l * 640 * 128,
                                          rg_bias + (size_t)l * CC, typeStart, h, h16, SS(s_mn), n);

        k_mf<128, 256, true, true, true, true, true, 1><<<dim3(gm64, 2, 2), 256, 0, stream>>>(
            h16, pw_mw0 + (size_t)l * 2 * 128 * 256, mb0 + (size_t)l * TT * HH,
            SS(s_mn), mn_g + (size_t)l * TT * CC, mn_b + (size_t)l * TT * CC,
            typeStart, nullptr, A256b, SS(s_mg), 0, n);
        if (l == 0)
            k_mf<256, 128, true, true, true, true, true, 2><<<dim3(gm64, 2, 1), 256, 0, stream>>>(
                A256b, pw_mw1 + (size_t)l * 2 * 256 * 128, mb1 + (size_t)l * TT * CC,
                SS(s_mg), mg0 + (size_t)l * TT * HH, mbe0 + (size_t)l * TT * HH,
                typeStart, h, h16, SS(s_nx), 0, n);
        else
            k_mf<256, 128, true, true, true, true, false, 2><<<dim3(gm64, 2, 1), 256, 0, stream>>>(
                A256b, pw_mw1 + (size_t)l * 2 * 256 * 128, mb1 + (size_t)l * TT * CC,
                SS(s_mg), mg0 + (size_t)l * TT * HH, mbe0 + (size_t)l * TT * HH,
                typeStart, h, h16, nullptr, 0, n);
    }

    // ---- readout ----
    k_mf<128, 256, true, true, false, true, true, 1><<<dim3(gm64, 2, 2), 256, 0, stream>>>(
        h16, pw_ro0, ro_b0, nullptr, nullptr, nullptr, typeStart, nullptr, A256b, SS(8), 0, n);
    k_coef<<<1, 512, 0, stream>>>(SS(8), typeStart, ro_g0, ro_be0, scale, shift, HH);
    k_ro1<<<(n + 63) / 64, 256, 0, stream>>>(A256b, perm, typeStart, ro_w1, ro_b1, scale, shift, out, n);
}

// Round 12
// 703.992 us; speedup vs baseline: 1.4767x; 1.4767x over previous
//
#include <hip/hip_runtime.h>

#define TT 2
#define RR 4
#define LL 2
#define DIN 16
#define HH 256
#define CC 128
#define DOUT 4
#define EPS 1e-5f
#define NB 32   // stat buckets
#define NBG 16  // gram buckets

typedef float v4f __attribute__((ext_vector_type(4)));
typedef short bf16x8 __attribute__((ext_vector_type(8)));

__device__ __forceinline__ ushort f2bf(float x) {
    uint u = __float_as_uint(x);
    return (ushort)((u + 0x7fffu + ((u >> 16) & 1u)) >> 16);
}
__device__ __forceinline__ float bf2f(ushort h) { return __uint_as_float(((uint)h) << 16); }
__device__ __forceinline__ int swc(int c) { return c ^ ((c >> 3) & 7); }
__device__ __forceinline__ uint pack2(float x, float y) {
    return (uint)f2bf(x) | ((uint)f2bf(y) << 16);
}

// ---------------------------------------------------------------------------
// hierarchical exclusive scan
__global__ __launch_bounds__(1024) void k_scan1(const int* __restrict__ in, int* __restrict__ out,
                                                int* __restrict__ part, int n) {
    __shared__ int sm[1024];
    const int tid = threadIdx.x;
    const int i = blockIdx.x * 1024 + tid;
    const int v = (i < n) ? in[i] : 0;
    sm[tid] = v;
    __syncthreads();
    for (int off = 1; off < 1024; off <<= 1) {
        const int u = (tid >= off) ? sm[tid - off] : 0;
        __syncthreads();
        sm[tid] += u;
        __syncthreads();
    }
    if (i < n) out[i] = sm[tid] - v;
    if (tid == 1023) part[blockIdx.x] = sm[1023];
}

__global__ __launch_bounds__(1024) void k_scan2(int* __restrict__ part, int nb) {
    __shared__ int sm[1024];
    const int tid = threadIdx.x;
    const int v = (tid < nb) ? part[tid] : 0;
    sm[tid] = v;
    __syncthreads();
    for (int off = 1; off < 1024; off <<= 1) {
        const int u = (tid >= off) ? sm[tid - off] : 0;
        __syncthreads();
        sm[tid] += u;
        __syncthreads();
    }
    if (tid < nb) part[tid] = sm[tid] - v;
    if (tid == nb - 1) part[nb] = sm[tid];
}

// scan3 + optional typeStart write (pscan path) + optional dual write (cursor copy)
__global__ __launch_bounds__(1024) void k_scan3(int* __restrict__ arr, const int* __restrict__ part,
                                                int n, int nb, int* __restrict__ typeStart,
                                                int* __restrict__ out2) {
    const int i = blockIdx.x * 1024 + threadIdx.x;
    if (i < n) {
        const int v = arr[i] + part[i >> 10];
        arr[i] = v;
        if (out2) out2[i] = v;
    } else if (i == n) {
        const int total = part[nb];
        arr[n] = total;
        if (typeStart) { typeStart[0] = 0; typeStart[1] = n - total; typeStart[2] = n; }
    }
}

__global__ __launch_bounds__(256) void k_build_perm(const int* __restrict__ nt, const int* __restrict__ pscan,
                                                    const int* __restrict__ typeStart, int* __restrict__ perm,
                                                    int* __restrict__ inv, int n) {
    const int i = blockIdx.x * 256 + threadIdx.x;
    if (i >= n) return;
    const int s1 = pscan[i];
    const int pos = nt[i] ? (typeStart[1] + s1) : (i - s1);
    perm[pos] = i;
    inv[i] = pos;
}

__global__ __launch_bounds__(256) void k_deg2(const int* __restrict__ dstv, const int* __restrict__ et,
                                              const int* __restrict__ inv, int* __restrict__ rowp2, int nE) {
    const int e = blockIdx.x * 256 + threadIdx.x;
    if (e < nE) atomicAdd(&rowp2[inv[dstv[e]] * 4 + et[e]], 1);
}

__global__ __launch_bounds__(256) void k_fill2(const int* __restrict__ srcv, const int* __restrict__ dstv,
                                               const int* __restrict__ et, const int* __restrict__ inv,
                                               int* __restrict__ cur, int* __restrict__ csr, int nE) {
    const int e = blockIdx.x * 256 + threadIdx.x;
    if (e < nE) {
        const int pos = atomicAdd(&cur[inv[dstv[e]] * 4 + et[e]], 1);
        csr[pos] = inv[srcv[e]];
    }
}

// ---------------------------------------------------------------------------
// all regular weight packs in one kernel: [nmat][K][N] f32 -> [mat][K/8][N][8] bf16
__global__ __launch_bounds__(256) void k_packall(const float* __restrict__ ri_w1, const float* __restrict__ mw0,
                                                 const float* __restrict__ mw1, const float* __restrict__ ro_w0,
                                                 ushort* __restrict__ p_ri1, ushort* __restrict__ p_mw0,
                                                 ushort* __restrict__ p_mw1, ushort* __restrict__ p_ro0) {
    for (long long idx = (long long)blockIdx.x * 256 + threadIdx.x; idx < 393216;
         idx += (long long)gridDim.x * 256) {
        const float* src; ushort* dst; int K, N; long long lo;
        if (idx < 65536)       { src = ri_w1; dst = p_ri1; K = 256; N = 128; lo = idx; }
        else if (idx < 196608) { src = mw0;   dst = p_mw0; K = 128; N = 256; lo = idx - 65536; }
        else if (idx < 327680) { src = mw1;   dst = p_mw1; K = 256; N = 128; lo = idx - 196608; }
        else                   { src = ro_w0; dst = p_ro0; K = 128; N = 256; lo = idx - 327680; }
        const int kn = K * N;
        const int mat = (int)(lo / kn);
        const int rem = (int)(lo - (long long)mat * kn);
        const int k = rem / N, col = rem % N;
        dst[((size_t)mat * (K / 8) + (k >> 3)) * N * 8 + (size_t)col * 8 + (k & 7)] = f2bf(src[lo]);
    }
}

// conv stacked W: rows 0..511 = rg_w[r][kin][col], rows 512..639 = root[k][col]; blockIdx.y = layer
__global__ __launch_bounds__(256) void k_pack_conv(const float* __restrict__ rgw_all,
                                                   const float* __restrict__ root_all,
                                                   ushort* __restrict__ dst_all) {
    const int idx = blockIdx.x * 256 + threadIdx.x;
    if (idx >= 640 * 128) return;
    const int l = blockIdx.y;
    const float* rgw = rgw_all + (size_t)l * RR * CC * CC;
    const float* root = root_all + (size_t)l * CC * CC;
    ushort* dst = dst_all + (size_t)l * 640 * 128;
    const int k = idx >> 7, col = idx & 127;
    const float v = (k < 512) ? rgw[(((k >> 7) * CC) + (k & 127)) * CC + col]
                              : root[(size_t)(k - 512) * CC + col];
    dst[((size_t)(k >> 3) * CC + col) * 8 + (k & 7)] = f2bf(v);
}

// ---------------------------------------------------------------------------
// y16 = act(bn(h))  (f32 h master -> bf16); self-computes BN coefs from stats
__global__ __launch_bounds__(256) void k_bnact(const float* __restrict__ h, const float* __restrict__ stat_in,
                                               const float* __restrict__ gg, const float* __restrict__ bb,
                                               const int* __restrict__ typeStart,
                                               ushort* __restrict__ y16, int n) {
    __shared__ float scs[2 * CC];
    __shared__ float sfs[2 * CC];
    const int tid = threadIdx.x;
    for (int idx = tid; idx < 2 * CC; idx += 256) {
        const int t = idx >> 7;
        float s = 0.f, q = 0.f;
        for (int b = 0; b < NB; ++b) {
            s += stat_in[(size_t)b * 1024 + idx];
            q += stat_in[(size_t)b * 1024 + 512 + idx];
        }
        const float cnt = fmaxf((float)(typeStart[t + 1] - typeStart[t]), 1.f);
        const float mean = s / cnt;
        const float var = q / cnt - mean * mean;
        const float sc = gg[idx] * rsqrtf(var + EPS);
        scs[idx] = sc;
        sfs[idx] = bb[idx] - mean * sc;
    }
    __syncthreads();
    const int c0 = typeStart[1];
    const long long total = (long long)n * 32;
    for (long long idx = (long long)blockIdx.x * 256 + threadIdx.x; idx < total;
         idx += (long long)gridDim.x * 256) {
        const int i = (int)(idx >> 5), cq = (int)(idx & 31);
        const int tb = (i >= c0) ? CC : 0;
        const v4f v = *(const v4f*)(h + (size_t)i * CC + cq * 4);
        float o[4];
#pragma unroll
        for (int j = 0; j < 4; ++j) {
            const float vv = fmaf(v[j], scs[tb + cq * 4 + j], sfs[tb + cq * 4 + j]);
            o[j] = fmaxf(vv, 0.01f * vv);
        }
        uint2 p = make_uint2(pack2(o[0], o[1]), pack2(o[2], o[3]));
        *(uint2*)((uint*)y16 + (size_t)i * 64 + cq * 2) = p;
    }
}

// ---------------------------------------------------------------------------
// 4-relation aggregation of precomputed y16 -> bf16 buf [rows][512]
__global__ __launch_bounds__(256) void k_agg4(const ushort* __restrict__ y16, const int* __restrict__ rowp2,
                                              const int* __restrict__ csr, ushort* __restrict__ buf,
                                              int q0, int q1) {
    const int wid = threadIdx.x >> 6, lane = threadIdx.x & 63;
    const int i = q0 + blockIdx.x * 4 + wid;
    if (i >= q1) return;
    const uint* y32 = (const uint*)y16;
    float2 a0 = {0.f, 0.f}, a1 = {0.f, 0.f}, a2 = {0.f, 0.f}, a3 = {0.f, 0.f};
    const int e0 = rowp2[4 * i], b1 = rowp2[4 * i + 1], b2 = rowp2[4 * i + 2],
              b3 = rowp2[4 * i + 3], e1 = rowp2[4 * i + 4];
    for (int e = e0; e < e1; e += 64) {
        const int cnt = min(64, e1 - e);
        int pk = (lane < cnt) ? csr[e + lane] : 0;
        for (int j = 0; j < cnt; ++j) {
            const int s = __shfl(pk, j);
            const uint u = y32[(size_t)s * 64 + lane];
            const float vx = bf2f((ushort)(u & 0xffff));
            const float vy = bf2f((ushort)(u >> 16));
            const int idx = e + j;
            if (idx < b1)      { a0.x += vx; a0.y += vy; }
            else if (idx < b2) { a1.x += vx; a1.y += vy; }
            else if (idx < b3) { a2.x += vx; a2.y += vy; }
            else               { a3.x += vx; a3.y += vy; }
        }
    }
    uint* brow = (uint*)buf + (size_t)(i - q0) * 256;
    brow[0 * 64 + lane] = pack2(a0.x, a0.y);
    brow[1 * 64 + lane] = pack2(a1.x, a1.y);
    brow[2 * 64 + lane] = pack2(a2.x, a2.y);
    brow[3 * 64 + lane] = pack2(a3.x, a3.y);
}

// ---------------------------------------------------------------------------
// Gram matrix of x per type: gram[t][bucket][272] = {G[256], s[16]}
__global__ __launch_bounds__(256) void k_gram(const float* __restrict__ x, const int* __restrict__ perm,
                                              const int* __restrict__ typeStart, float* __restrict__ gram) {
    __shared__ float Xs[256][17];
    const int tid = threadIdx.x;
    const int t = blockIdx.y;
    const int rbeg = typeStart[t], rend = typeStart[t + 1];
    const int r0 = rbeg + blockIdx.x * 1024;
    if (r0 >= rend) return;
    const int i = tid >> 4, j = tid & 15;
    float acc = 0.f, sacc = 0.f;
    for (int rr = 0; rr < 4; ++rr) {
        const int gr = r0 + rr * 256 + tid;
        v4f x0 = 0.f, x1 = 0.f, x2 = 0.f, x3 = 0.f;
        if (gr < rend) {
            const float* xr = x + (size_t)perm[gr] * DIN;
            x0 = *(const v4f*)xr; x1 = *(const v4f*)(xr + 4);
            x2 = *(const v4f*)(xr + 8); x3 = *(const v4f*)(xr + 12);
        }
        __syncthreads();
#pragma unroll
        for (int e = 0; e < 4; ++e) { Xs[tid][e] = x0[e]; Xs[tid][4 + e] = x1[e];
                                      Xs[tid][8 + e] = x2[e]; Xs[tid][12 + e] = x3[e]; }
        __syncthreads();
        for (int r = 0; r < 256; ++r) acc += Xs[r][i] * Xs[r][j];
        if (tid < 16)
            for (int r = 0; r < 256; ++r) sacc += Xs[r][tid];
        __syncthreads();
    }
    float* gb = gram + ((size_t)t * NBG + (blockIdx.x & (NBG - 1))) * 272;
    atomicAdd(&gb[tid], acc);
    if (tid < 16) atomicAdd(&gb[256 + tid], sacc);
}

// analytic readin BN coef, folded into effective W0', b0'
__global__ __launch_bounds__(512) void k_ri_coef(const float* __restrict__ gram, const int* __restrict__ typeStart,
                                                 const float* __restrict__ ri_w0, const float* __restrict__ ri_b0,
                                                 const float* __restrict__ g, const float* __restrict__ be,
                                                 float* __restrict__ w0eff, float* __restrict__ b0eff) {
    __shared__ float G[2][272];
    const int tid = threadIdx.x;
    for (int idx = tid; idx < 2 * 272; idx += 512) {
        const int tt = idx / 272, k = idx % 272;
        float s = 0.f;
        for (int b = 0; b < NBG; ++b) s += gram[((size_t)tt * NBG + b) * 272 + k];
        G[tt][k] = s;
    }
    __syncthreads();
    const int t = tid >> 8, c = tid & 255;
    float wv[16];
#pragma unroll
    for (int k = 0; k < 16; ++k) wv[k] = ri_w0[((size_t)t * 16 + k) * HH + c];
    const float b = ri_b0[t * HH + c];
    const float cnt = fmaxf((float)(typeStart[t + 1] - typeStart[t]), 1.f);
    float sw = 0.f;
#pragma unroll
    for (int k = 0; k < 16; ++k) sw += G[t][256 + k] * wv[k];
    const float mean = (sw + cnt * b) / cnt;
    float e2 = 0.f;
#pragma unroll
    for (int i = 0; i < 16; ++i) {
        const float wi = wv[i];
#pragma unroll
        for (int j = 0; j < 16; ++j) e2 += wi * wv[j] * G[t][i * 16 + j];
    }
    e2 = (e2 + 2.f * b * sw + cnt * b * b) / cnt;
    const float var = e2 - mean * mean;
    const float sc = g[t * HH + c] * rsqrtf(var + EPS);
    const float sf = be[t * HH + c] - mean * sc;
    b0eff[t * HH + c] = b * sc + sf;
#pragma unroll
    for (int k = 0; k < 16; ++k) w0eff[((size_t)t * 16 + k) * HH + c] = wv[k] * sc;
}

// ---------------------------------------------------------------------------
// fused readin: h = act(x@W0'+b0') @ ri_w1 + ri_b1 ; writes h, h16, stats slot
__global__ __launch_bounds__(256) void k_readin(const float* __restrict__ x, const int* __restrict__ perm,
                                                const int* __restrict__ typeStart,
                                                const float* __restrict__ w0eff, const float* __restrict__ b0eff,
                                                const ushort* __restrict__ Wp, const float* __restrict__ b1,
                                                float* __restrict__ h, ushort* __restrict__ h16,
                                                float* __restrict__ stat) {
    __shared__ float Xs[128][17];
    __shared__ float W0s[16][256];
    __shared__ float b0s[256];
    __shared__ ushort As[128][40];
    __shared__ ushort Ws[4][128][8];

    const int tid = threadIdx.x;
    const int lane = tid & 63;
    const int wid = tid >> 6;
    const int woffm = (wid >> 1) * 64, woffn = (wid & 1) * 64;
    const int t = blockIdx.y;
    const int rbeg = typeStart[t], rend = typeStart[t + 1];
    const int r0 = rbeg + blockIdx.x * 128;
    if (r0 >= rend) return;

    for (int idx = tid; idx < 16 * 256; idx += 256) W0s[idx >> 8][idx & 255] = w0eff[(size_t)t * 4096 + idx];
    if (tid < 256) b0s[tid] = b0eff[t * 256 + tid];

    const int srow = tid >> 1, half = tid & 1;
    const int sgr = r0 + srow;
    const bool svalid = sgr < rend;
    {
        v4f x0 = 0.f, x1 = 0.f;
        if (svalid) {
            const float* xr = x + (size_t)perm[sgr] * DIN + half * 8;
            x0 = *(const v4f*)xr; x1 = *(const v4f*)(xr + 4);
        }
#pragma unroll
        for (int e = 0; e < 4; ++e) { Xs[srow][half * 8 + e] = x0[e]; Xs[srow][half * 8 + 4 + e] = x1[e]; }
    }
    __syncthreads();
    float xr[16];
#pragma unroll
    for (int k = 0; k < 16; ++k) xr[k] = Xs[srow][k];

    v4f acc[4][4];
#pragma unroll
    for (int mt = 0; mt < 4; ++mt)
#pragma unroll
        for (int nt = 0; nt < 4; ++nt) acc[mt][nt] = (v4f){0.f, 0.f, 0.f, 0.f};

    const size_t wmat = (size_t)t * 256 * 128;
    const int wcp = tid & 63;

    for (int kt = 0; kt < 8; ++kt) {
        const int k0 = kt * 32;
        ushort hA[16];
#pragma unroll
        for (int c2 = 0; c2 < 16; ++c2) {
            const int col = k0 + half * 16 + c2;
            float d = b0s[col];
#pragma unroll
            for (int k = 0; k < 16; ++k) d = fmaf(xr[k], W0s[k][col], d);
            d = fmaxf(d, 0.01f * d);
            hA[c2] = f2bf(d);
        }
        const ushort* wsrc = Wp + wmat + ((size_t)(k0 / 8 + wid) * 128) * 8 + (size_t)wcp * 16;
        const uint4 w0 = *(const uint4*)wsrc;
        const uint4 w1 = *(const uint4*)(wsrc + 8);
        __syncthreads();
        *(uint4*)&As[srow][half * 16] = *(uint4*)&hA[0];
        *(uint4*)&As[srow][half * 16 + 8] = *(uint4*)&hA[8];
        *(uint4*)&Ws[wid][swc(wcp * 2)][0] = w0;
        *(uint4*)&Ws[wid][swc(wcp * 2 + 1)][0] = w1;
        __syncthreads();
        const int afr = lane & 15;
        const int akg = (lane >> 4) * 8;
        bf16x8 aF[4], wf[4];
#pragma unroll
        for (int mt = 0; mt < 4; ++mt) aF[mt] = *(const bf16x8*)&As[woffm + mt * 16 + afr][akg];
#pragma unroll
        for (int nt = 0; nt < 4; ++nt) wf[nt] = *(const bf16x8*)&Ws[lane >> 4][swc(woffn + nt * 16 + afr)][0];
#pragma unroll
        for (int mt = 0; mt < 4; ++mt)
#pragma unroll
            for (int nt = 0; nt < 4; ++nt)
                acc[mt][nt] = __builtin_amdgcn_mfma_f32_16x16x32_bf16(aF[mt], wf[nt], acc[mt][nt], 0, 0, 0);
    }

    float bv[4];
#pragma unroll
    for (int nt = 0; nt < 4; ++nt) bv[nt] = b1[t * 128 + woffn + nt * 16 + (lane & 15)];
    float cs[4] = {0.f, 0.f, 0.f, 0.f}, cq[4] = {0.f, 0.f, 0.f, 0.f};
#pragma unroll
    for (int mt = 0; mt < 4; ++mt) {
        const int grow = r0 + woffm + mt * 16 + (lane >> 4) * 4;
#pragma unroll
        for (int nt = 0; nt < 4; ++nt) {
            const int gcol = woffn + nt * 16 + (lane & 15);
#pragma unroll
            for (int rg = 0; rg < 4; ++rg) {
                const int gr = grow + rg;
                if (gr < rend) {
                    const float v = acc[mt][nt][rg] + bv[nt];
                    const size_t o = (size_t)gr * 128 + gcol;
                    h[o] = v;
                    h16[o] = f2bf(v);
                    cs[nt] += v; cq[nt] += v * v;
                }
            }
        }
    }
    float* sb = stat + (size_t)(blockIdx.x & (NB - 1)) * 1024;
#pragma unroll
    for (int nt = 0; nt < 4; ++nt) {
        float s = cs[nt], q = cq[nt];
        s += __shfl_xor(s, 16); q += __shfl_xor(q, 16);
        s += __shfl_xor(s, 32); q += __shfl_xor(q, 32);
        if (lane < 16) {
            const int col = t * 128 + woffn + nt * 16 + lane;
            atomicAdd(&sb[col], s);
            atomicAdd(&sb[512 + col], q);
        }
    }
}

// ---------------------------------------------------------------------------
// LDS-staged MFMA GEMM, BM=64 tile, double-buffered LDS, depth-2 prefetch,
// ONE barrier per k-step. X bf16 row-linear (rows offset rbase, stride XSTR).
// CROOT: K=640 conv split operand (buf[512-wide] + y16[128-wide] tail).
// BNIN: self-computed BN coefs (stat_in,g,be) + leaky on input.
// OUTMODE 0: Y=f32; 1: Y16=bf16; 2: h-accumulate (Y+=, Y16=bf16(h)).
template <int K, int OUTW, bool TYPED, bool WHET, bool CROOT, bool BNIN,
          bool BHET, bool STATS, int OUTMODE>
__global__ __launch_bounds__(256) void k_mf(
    const ushort* __restrict__ Xb, const ushort* __restrict__ Xb2,
    const ushort* __restrict__ Wp, const float* __restrict__ Bb,
    const float* __restrict__ stat_in, const float* __restrict__ gg,
    const float* __restrict__ bb, const int* __restrict__ typeStart,
    float* __restrict__ Y, ushort* __restrict__ Y16, float* __restrict__ stat,
    int rbase, int rbeg_u, int rend_u) {
    constexpr int NT = K / 32;
    constexpr int XSTR = CROOT ? 512 : K;

    __shared__ ushort As[2][64][40];
    __shared__ ushort Ws[2][4][128][8];
    __shared__ float csh[BNIN ? K : 1];
    __shared__ float cfh[BNIN ? K : 1];

    const int tid = threadIdx.x;
    const int lane = tid & 63;
    const int wid = tid >> 6;
    const int kgrp = lane >> 4, fr = lane & 15;
    const int woffm = (wid >> 1) * 32;
    const int woffn = (wid & 1) * 64;

    int t = 0, rbeg = rbeg_u, rend = rend_u;
    if constexpr (TYPED) { t = blockIdx.y; rbeg = typeStart[t]; rend = typeStart[t + 1]; }
    const int r0 = rbeg + blockIdx.x * 64;
    if (r0 >= rend) return;
    const int zoff = (OUTW == 256) ? blockIdx.z * 128 : 0;

    if constexpr (BNIN) {
        const float cnt = fmaxf((float)(typeStart[t + 1] - typeStart[t]), 1.f);
        for (int k = tid; k < K; k += 256) {
            float s = 0.f, q = 0.f;
            for (int b = 0; b < NB; ++b) {
                s += stat_in[(size_t)b * 1024 + t * K + k];
                q += stat_in[(size_t)b * 1024 + 512 + t * K + k];
            }
            const float mean = s / cnt;
            const float var = q / cnt - mean * mean;
            const float sc = gg[t * K + k] * rsqrtf(var + EPS);
            csh[k] = sc;
            cfh[k] = bb[t * K + k] - mean * sc;
        }
        __syncthreads();
    }

    const int srow = tid >> 2, skq = tid & 3;
    const int sgr = r0 + srow;
    const bool sv = sgr < rend;
    const int wcp = tid & 63;
    const size_t wmat = (size_t)(WHET ? t : 0) * K * OUTW;

    auto LOADA = [&](int kt) -> uint4 {
        const int k0 = kt * 32;
        uint4 a = make_uint4(0, 0, 0, 0);
        if (sv) {
            const ushort* p;
            if constexpr (CROOT) {
                p = (k0 >= 512) ? (Xb2 + (size_t)sgr * 128 + (k0 - 512) + skq * 8)
                                : (Xb + (size_t)(sgr - rbase) * XSTR + k0 + skq * 8);
            } else {
                p = Xb + (size_t)(sgr - rbase) * XSTR + k0 + skq * 8;
            }
            a = *(const uint4*)p;
        }
        if constexpr (BNIN) {
            uint ua[4] = {a.x, a.y, a.z, a.w};
#pragma unroll
            for (int e = 0; e < 4; ++e) {
                const int k = kt * 32 + skq * 8 + 2 * e;
                float f0 = fmaf(bf2f((ushort)(ua[e] & 0xffff)), csh[k], cfh[k]);
                float f1 = fmaf(bf2f((ushort)(ua[e] >> 16)), csh[k + 1], cfh[k + 1]);
                f0 = fmaxf(f0, 0.01f * f0);
                f1 = fmaxf(f1, 0.01f * f1);
                ua[e] = pack2(f0, f1);
            }
            a = make_uint4(ua[0], ua[1], ua[2], ua[3]);
        }
        return a;
    };
    auto LOADW = [&](int kt, uint4& w0, uint4& w1) {
        const ushort* wsrc = Wp + wmat + ((size_t)(kt * 4 + wid) * OUTW + zoff) * 8 + (size_t)wcp * 16;
        w0 = *(const uint4*)wsrc;
        w1 = *(const uint4*)(wsrc + 8);
    };
    auto STORE = [&](int b, const uint4& a, const uint4& w0, const uint4& w1) {
        *(uint4*)&As[b][srow][skq * 8] = a;
        *(uint4*)&Ws[b][wid][swc(wcp * 2)][0] = w0;
        *(uint4*)&Ws[b][wid][swc(wcp * 2 + 1)][0] = w1;
    };

    v4f acc[2][4];
#pragma unroll
    for (int mt = 0; mt < 2; ++mt)
#pragma unroll
        for (int nt = 0; nt < 4; ++nt) acc[mt][nt] = (v4f){0.f, 0.f, 0.f, 0.f};

    auto MSTEP = [&](int b) {
        const bf16x8 aF0 = *(const bf16x8*)&As[b][woffm + fr][kgrp * 8];
        const bf16x8 aF1 = *(const bf16x8*)&As[b][woffm + 16 + fr][kgrp * 8];
        bf16x8 wf[4];
#pragma unroll
        for (int nt = 0; nt < 4; ++nt)
            wf[nt] = *(const bf16x8*)&Ws[b][kgrp][swc(woffn + nt * 16 + fr)][0];
#pragma unroll
        for (int nt = 0; nt < 4; ++nt) {
            acc[0][nt] = __builtin_amdgcn_mfma_f32_16x16x32_bf16(aF0, wf[nt], acc[0][nt], 0, 0, 0);
            acc[1][nt] = __builtin_amdgcn_mfma_f32_16x16x32_bf16(aF1, wf[nt], acc[1][nt], 0, 0, 0);
        }
    };

    uint4 aA = make_uint4(0, 0, 0, 0), wA0 = aA, wA1 = aA;
    uint4 aB = aA, wB0 = aA, wB1 = aA;
    {
        uint4 a0 = LOADA(0), w0, w1;
        LOADW(0, w0, w1);
        STORE(0, a0, w0, w1);
    }
    if (NT > 1) { aA = LOADA(1); LOADW(1, wA0, wA1); }
    if (NT > 2) { aB = LOADA(2); LOADW(2, wB0, wB1); }
    __syncthreads();

#pragma unroll
    for (int kt = 0; kt < NT; kt += 2) {
        MSTEP(0);
        {
            STORE(1, aA, wA0, wA1);
            if (kt + 3 < NT) { aA = LOADA(kt + 3); LOADW(kt + 3, wA0, wA1); }
            __syncthreads();
        }
        MSTEP(1);
        if (kt + 2 < NT) {
            STORE(0, aB, wB0, wB1);
            if (kt + 4 < NT) { aB = LOADA(kt + 4); LOADW(kt + 4, wB0, wB1); }
            __syncthreads();
        }
    }

    // ---- epilogue ----
    const float* BbT = Bb + (BHET ? (size_t)t * OUTW : 0);
    float bv[4];
#pragma unroll
    for (int nt = 0; nt < 4; ++nt) bv[nt] = BbT[zoff + woffn + nt * 16 + fr];
    const int c0 = (STATS && !TYPED) ? typeStart[1] : 0;
    float cs0[4] = {0.f, 0.f, 0.f, 0.f}, cq0[4] = {0.f, 0.f, 0.f, 0.f};
    float cs1[4] = {0.f, 0.f, 0.f, 0.f}, cq1[4] = {0.f, 0.f, 0.f, 0.f};
#pragma unroll
    for (int mt = 0; mt < 2; ++mt) {
        const int grow = r0 + woffm + mt * 16 + kgrp * 4;
#pragma unroll
        for (int nt = 0; nt < 4; ++nt) {
            const int gcol = zoff + woffn + nt * 16 + fr;
#pragma unroll
            for (int rg = 0; rg < 4; ++rg) {
                const int gr = grow + rg;
                if (gr < rend) {
                    float v = acc[mt][nt][rg] + bv[nt];
                    const size_t o = (size_t)gr * OUTW + gcol;
                    if constexpr (OUTMODE == 0) Y[o] = v;
                    if constexpr (OUTMODE == 1) Y16[o] = f2bf(v);
                    if constexpr (OUTMODE == 2) {
                        const float hv = Y[o] + v;
                        Y[o] = hv;
                        Y16[o] = f2bf(hv);
                        v = hv;
                    }
                    if constexpr (STATS) {
                        if (TYPED || gr < c0) { cs0[nt] += v; cq0[nt] += v * v; }
                        else                  { cs1[nt] += v; cq1[nt] += v * v; }
                    }
                }
            }
        }
    }
    if constexpr (STATS) {
        float* sb = stat + (size_t)(blockIdx.x & (NB - 1)) * 1024;
#pragma unroll
        for (int nt = 0; nt < 4; ++nt) {
            float s = cs0[nt], q = cq0[nt];
            s += __shfl_xor(s, 16); q += __shfl_xor(q, 16);
            s += __shfl_xor(s, 32); q += __shfl_xor(q, 32);
            if (lane < 16) {
                const int col = t * OUTW + zoff + woffn + nt * 16 + lane;
                atomicAdd(&sb[col], s);
                atomicAdd(&sb[512 + col], q);
            }
            if constexpr (!TYPED) {
                float s1 = cs1[nt], q1 = cq1[nt];
                s1 += __shfl_xor(s1, 16); q1 += __shfl_xor(q1, 16);
                s1 += __shfl_xor(s1, 32); q1 += __shfl_xor(q1, 32);
                if (lane < 16) {
                    const int col = OUTW + zoff + woffn + nt * 16 + lane;
                    atomicAdd(&sb[col], s1);
                    atomicAdd(&sb[512 + col], q1);
                }
            }
        }
    }
}

// ---------------------------------------------------------------------------
// readout stage 2: out[perm[i]] = act(bn(A256b[i])) @ ro_w1[t] + ro_b1[t]
// self-computes BN coefs from stat buckets (replaces k_coef)
__global__ __launch_bounds__(256) void k_ro1(const ushort* __restrict__ A256b, const int* __restrict__ perm,
                                             const int* __restrict__ typeStart, const float* __restrict__ ro_w1,
                                             const float* __restrict__ ro_b1, const float* __restrict__ stat_in,
                                             const float* __restrict__ gg, const float* __restrict__ bb,
                                             float* __restrict__ out, int n) {
    __shared__ float W1s[2][256][4];
    __shared__ float scs[512];
    __shared__ float sfs[512];
    const int tid = threadIdx.x;
    for (int idx = tid; idx < 2048; idx += 256) {
        const int t = idx >> 10, rem = idx & 1023;
        W1s[t][rem >> 2][rem & 3] = ro_w1[idx];
    }
    for (int idx = tid; idx < 512; idx += 256) {
        const int t = idx >> 8;
        float s = 0.f, q = 0.f;
        for (int b = 0; b < NB; ++b) {
            s += stat_in[(size_t)b * 1024 + idx];
            q += stat_in[(size_t)b * 1024 + 512 + idx];
        }
        const float cnt = fmaxf((float)(typeStart[t + 1] - typeStart[t]), 1.f);
        const float mean = s / cnt;
        const float var = q / cnt - mean * mean;
        const float sc = gg[idx] * rsqrtf(var + EPS);
        scs[idx] = sc;
        sfs[idx] = bb[idx] - mean * sc;
    }
    __syncthreads();
    const int trow = tid >> 2, sub = tid & 3;
    const int gr = blockIdx.x * 64 + trow;
    if (gr >= n) return;
    const int c0 = typeStart[1];
    const int t = (gr >= c0) ? 1 : 0;
    v4f acc = 0.f;
    const ushort* ar = A256b + (size_t)gr * 256 + sub * 64;
#pragma unroll
    for (int q = 0; q < 8; ++q) {
        const uint4 u = *(const uint4*)(ar + q * 8);
        const uint uw[4] = {u.x, u.y, u.z, u.w};
#pragma unroll
        for (int e = 0; e < 4; ++e) {
#pragma unroll
            for (int hl = 0; hl < 2; ++hl) {
                const int col = sub * 64 + q * 8 + 2 * e + hl;
                const float v = bf2f((ushort)(hl ? (uw[e] >> 16) : (uw[e] & 0xffff)));
                float vv = fmaf(v, scs[t * 256 + col], sfs[t * 256 + col]);
                vv = fmaxf(vv, 0.01f * vv);
                acc += vv * *(const v4f*)&W1s[t][col][0];
            }
        }
    }
#pragma unroll
    for (int e = 0; e < 4; ++e) { acc[e] += __shfl_xor(acc[e], 1); acc[e] += __shfl_xor(acc[e], 2); }
    if (sub == 0) {
        acc += *(const v4f*)(ro_b1 + t * 4);
        *(v4f*)(out + (size_t)perm[gr] * 4) = acc;
    }
}

// ---------------------------------------------------------------------------
extern "C" void kernel_launch(void* const* d_in, const int* in_sizes, int n_in,
                              void* d_out, int out_size, void* d_ws, size_t ws_size,
                              hipStream_t stream) {
    const float* x = (const float*)d_in[0];
    const int* ei = (const int*)d_in[1];
    const int* nt = (const int*)d_in[2];
    const int* et = (const int*)d_in[3];
    const float* ri_w0 = (const float*)d_in[4];
    const float* ri_b0 = (const float*)d_in[5];
    const float* ri_g0 = (const float*)d_in[6];
    const float* ri_be0 = (const float*)d_in[7];
    const float* ri_w1 = (const float*)d_in[8];
    const float* ri_b1 = (const float*)d_in[9];
    const float* cn_g = (const float*)d_in[10];
    const float* cn_b = (const float*)d_in[11];
    const float* rg_w = (const float*)d_in[12];
    const float* rg_root = (const float*)d_in[13];
    const float* rg_bias = (const float*)d_in[14];
    const float* mn_g = (const float*)d_in[15];
    const float* mn_b = (const float*)d_in[16];
    const float* mw0 = (const float*)d_in[17];
    const float* mb0 = (const float*)d_in[18];
    const float* mg0 = (const float*)d_in[19];
    const float* mbe0 = (const float*)d_in[20];
    const float* mw1 = (const float*)d_in[21];
    const float* mb1 = (const float*)d_in[22];
    const float* ro_w0 = (const float*)d_in[23];
    const float* ro_b0 = (const float*)d_in[24];
    const float* ro_g0 = (const float*)d_in[25];
    const float* ro_be0 = (const float*)d_in[26];
    const float* ro_w1 = (const float*)d_in[27];
    const float* ro_b1 = (const float*)d_in[28];

    const int n = in_sizes[2];
    const int nE = in_sizes[3];
    const int* srcv = ei;
    const int* dstv = ei + nE;

    // ---- workspace ----
    char* w = (char*)d_ws;
    size_t off = 0;
    auto alloc = [&](size_t bytes) -> char* {
        char* p = w + off;
        off = (off + bytes + 255) & ~(size_t)255;
        return p;
    };
    float* h = (float*)alloc((size_t)n * CC * sizeof(float));
    ushort* h16 = (ushort*)alloc((size_t)(n + 128) * CC * sizeof(ushort));
    int* csr = (int*)alloc((size_t)nE * sizeof(int));
    int* rowp2 = (int*)alloc(((size_t)4 * n + 1) * sizeof(int));
    int* cur2 = (int*)alloc((size_t)4 * n * sizeof(int));
    int* perm = (int*)alloc((size_t)n * sizeof(int));
    int* inv = (int*)alloc((size_t)n * sizeof(int));
    int* pscan = (int*)alloc((size_t)(n + 1) * sizeof(int));
    int* part = (int*)alloc(2052 * sizeof(int));
    int* typeStart = (int*)alloc(64);
    float* statgram = (float*)alloc(((size_t)9 * NB * 1024 + 2 * NBG * 272) * sizeof(float));
    float* w0eff = (float*)alloc((size_t)2 * 16 * 256 * sizeof(float));
    float* b0eff = (float*)alloc(512 * sizeof(float));
    ushort* pw_ri1 = (ushort*)alloc(65536 * 2);
    ushort* pw_mw0 = (ushort*)alloc(131072 * 2);
    ushort* pw_mw1 = (ushort*)alloc(131072 * 2);
    ushort* pw_ro0 = (ushort*)alloc(65536 * 2);
    ushort* pw_conv = (ushort*)alloc(163840 * 2);
    char* region2 = alloc((size_t)(n + 128) * 512);  // A256b bf16 | y16 (disjoint lifetimes)
    if (ws_size < off) return;

    float* statbuf = statgram;
    float* gram = statgram + (size_t)9 * NB * 1024;
    ushort* A256b = (ushort*)region2;
    ushort* y16 = (ushort*)region2;  // first n*256 bytes of region2
    float* out = (float*)d_out;

    // remaining workspace -> conv aggregation buffer (bf16 [rows][512])
    ushort* buf = (ushort*)(w + off);
    const size_t bufBytes = (ws_size > off) ? (ws_size - off) : 0;
    const long long chkcap = (long long)(bufBytes / 1024) - 128;
    if (chkcap < 1024) return;
    int nchunk, CHK;
    if (chkcap >= n) { nchunk = 1; CHK = n; }
    else { nchunk = (int)((n + chkcap - 1) / chkcap); CHK = (n + nchunk - 1) / nchunk; }

    auto SS = [&](int slot) { return statbuf + (size_t)slot * NB * 1024; };

    const int gE = (nE + 255) / 256;
    const int gN = (n + 255) / 256;
    const int nb = (n + 1023) / 1024;
    const int m4 = 4 * n;
    const int nb2 = (m4 + 1023) / 1024;
    const int gmx = (n + 127) / 128;
    const int gm64 = (n + 63) / 64;

    // ---- weight packing ----
    k_packall<<<1536, 256, 0, stream>>>(ri_w1, mw0, mw1, ro_w0, pw_ri1, pw_mw0, pw_mw1, pw_ro0);
    k_pack_conv<<<dim3(320, 2), 256, 0, stream>>>(rg_w, rg_root, pw_conv);

    // ---- setup ----
    hipMemsetAsync(statgram, 0, ((size_t)9 * NB * 1024 + 2 * NBG * 272) * sizeof(float), stream);
    k_scan1<<<nb, 1024, 0, stream>>>(nt, pscan, part, n);
    k_scan2<<<1, 1024, 0, stream>>>(part, nb);
    k_scan3<<<(n + 1024) / 1024, 1024, 0, stream>>>(pscan, part, n, nb, typeStart, nullptr);
    k_build_perm<<<gN, 256, 0, stream>>>(nt, pscan, typeStart, perm, inv, n);
    hipMemsetAsync(rowp2, 0, ((size_t)m4 + 1) * sizeof(int), stream);
    k_deg2<<<gE, 256, 0, stream>>>(dstv, et, inv, rowp2, nE);
    k_scan1<<<nb2, 1024, 0, stream>>>(rowp2, rowp2, part, m4);
    k_scan2<<<1, 1024, 0, stream>>>(part, nb2);
    k_scan3<<<(m4 + 1024) / 1024, 1024, 0, stream>>>(rowp2, part, m4, nb2, nullptr, cur2);
    k_fill2<<<gE, 256, 0, stream>>>(srcv, dstv, et, inv, cur2, csr, nE);

    // ---- readin (fused): gram -> analytic coef -> x->h ----
    k_gram<<<dim3((n + 1023) / 1024, 2), 256, 0, stream>>>(x, perm, typeStart, gram);
    k_ri_coef<<<1, 512, 0, stream>>>(gram, typeStart, ri_w0, ri_b0, ri_g0, ri_be0, w0eff, b0eff);
    k_readin<<<dim3(gmx, 2), 256, 0, stream>>>(x, perm, typeStart, w0eff, b0eff, pw_ri1, ri_b1,
                                               h, h16, SS(1));

    // ---- RES+ layers ----
    for (int l = 0; l < LL; ++l) {
        const int s_cn = l ? 4 : 1, s_mn = l ? 5 : 2, s_mg = l ? 6 : 3, s_nx = l ? 7 : 4;
        k_bnact<<<1280, 256, 0, stream>>>(h, SS(s_cn), cn_g + (size_t)l * TT * CC,
                                          cn_b + (size_t)l * TT * CC, typeStart, y16, n);
        const ushort* wconv = pw_conv + (size_t)l * 640 * 128;
        for (int q0 = 0; q0 < n; q0 += CHK) {
            const int q1 = min(n, q0 + CHK);
            k_agg4<<<(q1 - q0 + 3) / 4, 256, 0, stream>>>(y16, rowp2, csr, buf, q0, q1);
            k_mf<640, 128, false, false, true, false, false, true, 2>
                <<<(q1 - q0 + 63) / 64, 256, 0, stream>>>(
                    buf, y16, wconv, rg_bias + (size_t)l * CC, nullptr, nullptr, nullptr,
                    typeStart, h, h16, SS(s_mn), q0, q0, q1);
        }

        k_mf<128, 256, true, true, false, true, true, true, 1><<<dim3(gm64, 2, 2), 256, 0, stream>>>(
            h16, nullptr, pw_mw0 + (size_t)l * 2 * 128 * 256, mb0 + (size_t)l * TT * HH,
            SS(s_mn), mn_g + (size_t)l * TT * CC, mn_b + (size_t)l * TT * CC,
            typeStart, nullptr, A256b, SS(s_mg), 0, 0, n);
        if (l == 0)
            k_mf<256, 128, true, true, false, true, true, true, 2><<<dim3(gm64, 2, 1), 256, 0, stream>>>(
                A256b, nullptr, pw_mw1 + (size_t)l * 2 * 256 * 128, mb1 + (size_t)l * TT * CC,
                SS(s_mg), mg0 + (size_t)l * TT * HH, mbe0 + (size_t)l * TT * HH,
                typeStart, h, h16, SS(s_nx), 0, 0, n);
        else
            k_mf<256, 128, true, true, false, true, true, false, 2><<<dim3(gm64, 2, 1), 256, 0, stream>>>(
                A256b, nullptr, pw_mw1 + (size_t)l * 2 * 256 * 128, mb1 + (size_t)l * TT * CC,
                SS(s_mg), mg0 + (size_t)l * TT * HH, mbe0 + (size_t)l * TT * HH,
                typeStart, h, h16, nullptr, 0, 0, n);
    }

    // ---- readout ----
    k_mf<128, 256, true, true, false, false, true, true, 1><<<dim3(gm64, 2, 2), 256, 0, stream>>>(
        h16, nullptr, pw_ro0, ro_b0, nullptr, nullptr, nullptr, typeStart, nullptr, A256b, SS(8), 0, 0, n);
    k_ro1<<<(n + 63) / 64, 256, 0, stream>>>(A256b, perm, typeStart, ro_w1, ro_b1,
                                             SS(8), ro_g0, ro_be0, out, n);
}